// Round 1
// 468.766 us; speedup vs baseline: 1.0957x; 1.0957x over previous
//
#include <hip/hip_runtime.h>
#include <hip/hip_bf16.h>
#include <math.h>
#include <stdint.h>

#define NHEADS 32
#define HDIM 128
#define POOLW 16
#define DMODEL 1536
#define SPOOL 512
#define HDTOT 4096   // NHEADS*HDIM
#define PEROWS 1024  // 2*SPOOL
#define NPAIR (SPOOL * SPOOL)   // 262144

typedef __hip_bfloat16 bf16;
typedef short short8 __attribute__((ext_vector_type(8)));
typedef short short4v __attribute__((ext_vector_type(4)));
typedef float f32x4 __attribute__((ext_vector_type(4)));

__device__ __forceinline__ float b2f(const bf16 v) { return __bfloat162float(v); }
__device__ __forceinline__ bf16 f2b(float v) { return __float2bfloat16(v); }
__device__ __forceinline__ short f2bs(float v) {
  bf16 b = __float2bfloat16(v);
  return *reinterpret_cast<short*>(&b);
}
__device__ __forceinline__ float bs2f(short s) {
  bf16 b = *reinterpret_cast<bf16*>(&s);
  return __bfloat162float(b);
}

__device__ __forceinline__ void gload_lds16(const void* g, void* l) {
  const __attribute__((address_space(1))) uint32_t* gp =
      (const __attribute__((address_space(1))) uint32_t*)(uintptr_t)g;
  __attribute__((address_space(3))) uint32_t* lp =
      (__attribute__((address_space(3))) uint32_t*)(uintptr_t)l;
  __builtin_amdgcn_global_load_lds(gp, lp, 16, 0, 0);
}

// ---------------------------------------------------------------------------
// K1: pool (mean 16) + RMSNorm + GELU -> bf16 xn, xg
// ---------------------------------------------------------------------------
__global__ __launch_bounds__(256) void pool_rms_gelu_bf(
    const float* __restrict__ x, const float* __restrict__ w_rms,
    bf16* __restrict__ xn, bf16* __restrict__ xg) {
  int sp = blockIdx.x;
  int tid = threadIdx.x;
  __shared__ float buf[DMODEL];
  __shared__ float red[256];
  const float* xrow = x + (size_t)sp * POOLW * DMODEL;
  float ss = 0.f;
  for (int d = tid; d < DMODEL; d += 256) {
    float s = 0.f;
#pragma unroll
    for (int p = 0; p < POOLW; ++p) s += xrow[p * DMODEL + d];
    s *= (1.0f / POOLW);
    buf[d] = s;
    ss += s * s;
  }
  red[tid] = ss;
  __syncthreads();
  for (int off = 128; off > 0; off >>= 1) {
    if (tid < off) red[tid] += red[tid + off];
    __syncthreads();
  }
  float rms = rsqrtf(red[0] / DMODEL + 1e-6f);
  for (int d = tid; d < DMODEL; d += 256) {
    float v = buf[d] * rms * w_rms[d];
    xn[(size_t)sp * DMODEL + d] = f2b(v);
    xg[(size_t)sp * DMODEL + d] = f2b(0.5f * v * (1.0f + erff(v * 0.70710678118654752f)));
  }
}

// ---------------------------------------------------------------------------
// K2a: suffix sums of W_pos rows.  SW0[g][j] = sum_{f>=g} W_pos[f][j] (g=0..32)
// ---------------------------------------------------------------------------
__global__ __launch_bounds__(256) void suffix_kernel(
    const float* __restrict__ W_pos, float* __restrict__ SW0, float* __restrict__ SW1) {
  int j = blockIdx.x * 256 + threadIdx.x;
  float s0 = 0.f, s1 = 0.f;
  SW0[32 * HDTOT + j] = 0.f;
  SW1[32 * HDTOT + j] = 0.f;
  for (int f = 31; f >= 0; --f) {
    s0 += W_pos[f * HDTOT + j];
    s1 += W_pos[(NHEADS + f) * HDTOT + j];
    SW0[f * HDTOT + j] = s0;
    SW1[f * HDTOT + j] = s1;
  }
}

// K2b: pe[p][j] = b_pos[j] + SW0[fmin][j] + sgn*SW1[fmin][j]
__global__ __launch_bounds__(256) void pos_enc2(
    const float* __restrict__ SW0, const float* __restrict__ SW1,
    const float* __restrict__ b_pos, bf16* __restrict__ pe) {
  int p = blockIdx.x;
  int rv = p - SPOOL;
  float dist = fabsf((float)rv);
  float sgn = (rv > 0) ? 1.f : ((rv < 0) ? -1.f : 0.f);
  double ls = log(481.0) / 32.0;  // log(512-32+1)/32
  int fm = 0;
#pragma unroll
  for (int f = 0; f < 32; ++f) {
    float cw = (float)f + expf((float)f * (float)ls);
    if (cw <= dist) fm = f + 1;
  }
  const float* r0 = SW0 + (size_t)fm * HDTOT;
  const float* r1 = SW1 + (size_t)fm * HDTOT;
  for (int j = threadIdx.x; j < HDTOT; j += 256) {
    pe[(size_t)p * HDTOT + j] = f2b(b_pos[j] + r0[j] + sgn * r1[j]);
  }
}

// ---------------------------------------------------------------------------
// K3: transpose + cast  in[R][C] fp32 -> out[C][R] bf16
// ---------------------------------------------------------------------------
__global__ __launch_bounds__(256) void transpose_cast(
    const float* __restrict__ in, bf16* __restrict__ out, int R, int C) {
  __shared__ float tile[32][33];
  int c0 = blockIdx.x * 32, r0 = blockIdx.y * 32;
  int tx = threadIdx.x & 31, ty = threadIdx.x >> 5;  // ty 0..7
  for (int i = ty; i < 32; i += 8) tile[i][tx] = in[(size_t)(r0 + i) * C + c0 + tx];
  __syncthreads();
  for (int i = ty; i < 32; i += 8) out[(size_t)(c0 + i) * R + r0 + tx] = f2b(tile[tx][i]);
}

// ---------------------------------------------------------------------------
// K4: rank-1 bias corrections: cq[h][p] = qrb_h . pe_h[p], ck likewise.
// ---------------------------------------------------------------------------
__global__ __launch_bounds__(256) void cqck_kernel(
    const float* __restrict__ qrb, const float* __restrict__ krb,
    const bf16* __restrict__ pe, float* __restrict__ cq, float* __restrict__ ck) {
  int h = blockIdx.x, pc = blockIdx.y;
  int t = threadIdx.x, w = t >> 6, lane = t & 63;
  float q0 = qrb[h * HDIM + lane], q1 = qrb[h * HDIM + 64 + lane];
  float k0 = krb[h * HDIM + lane], k1 = krb[h * HDIM + 64 + lane];
  for (int i = 0; i < 32; ++i) {
    int p = pc * 128 + w * 32 + i;
    float e0 = b2f(pe[(size_t)p * HDTOT + h * HDIM + lane]);
    float e1 = b2f(pe[(size_t)p * HDTOT + h * HDIM + 64 + lane]);
    float sq = q0 * e0 + q1 * e1;
    float sk = k0 * e0 + k1 * e1;
#pragma unroll
    for (int off = 32; off > 0; off >>= 1) {
      sq += __shfl_xor(sq, off, 64);
      sk += __shfl_xor(sk, off, 64);
    }
    if (lane == 0) {
      cq[h * PEROWS + p] = sq;
      ck[h * PEROWS + p] = sk;
    }
  }
}

// ---------------------------------------------------------------------------
// K5: bf16 MFMA GEMM:  C[M][N] = A[M][K] @ BT[N][K]^T  (both K-contiguous)
// 128x64 tile, BK=32, 256 threads.
// mode 0: fp32 store; mode 1: bf16 store;
// mode 2: diagonal remap + in-place RMW into SD[h][gm][kk=gn-512+gm]:
//         SD += 0.5*(v + extra[h][gn])   (only kk in [0,512))
// mode 3: diagonal remap, plain WRITE into SDT[h][gm=k][kk=q]:
//         SDT = 0.5*(v + extra[h][gn])   (only kk in [0,512))
//         (covers every (k,q) exactly once: gn = 512+q-k in [1,1023])
// modes 2/3: tiles that miss the diagonal band are skipped (322<=m0+n0<=1023).
// ---------------------------------------------------------------------------
__global__ __launch_bounds__(256) void gemm_mfma(
    const bf16* __restrict__ A, int lda, long long batchA,
    const bf16* __restrict__ BT, int ldb, long long batchB,
    void* __restrict__ C, int ldc, long long batchC,
    const float* __restrict__ extra, int mode, int M, int N, int K) {
  const int m0 = blockIdx.y * 128, n0 = blockIdx.x * 64;
  if (mode >= 2) {
    int s = m0 + n0;
    if (s < 322 || s > 1023) return;  // tile has no element on the diagonal band
  }
  __shared__ short Asub[128][32];
  __shared__ short Bsub[64][32];
  const int t = threadIdx.x;
  const int lane = t & 63;
  const int w = t >> 6;
  const int wm = (w >> 1) * 64, wn = (w & 1) * 32;
  const bf16* Ag = A + (size_t)blockIdx.z * batchA;
  const bf16* Bg = BT + (size_t)blockIdx.z * batchB;

  const int ar0 = t >> 2;
  const int as0 = t & 3;
  const int ao0 = as0 ^ (ar0 & 3);
  char* AsubB = (char*)&Asub[0][0];
  char* BsubB = (char*)&Bsub[0][0];
  char* ldsA0 = AsubB + w * 1024;
  char* ldsA1 = AsubB + 4096 + w * 1024;
  char* ldsB0 = BsubB + w * 1024;

  const int quad = lane >> 4, mr = lane & 15;
  f32x4 acc[4][2];
#pragma unroll
  for (int mi = 0; mi < 4; ++mi)
#pragma unroll
    for (int ni = 0; ni < 2; ++ni) acc[mi][ni] = (f32x4){0.f, 0.f, 0.f, 0.f};

  for (int k0 = 0; k0 < K; k0 += 32) {
    gload_lds16(Ag + (size_t)(m0 + ar0) * lda + k0 + ao0 * 8, ldsA0);
    gload_lds16(Ag + (size_t)(m0 + 64 + ar0) * lda + k0 + ao0 * 8, ldsA1);
    gload_lds16(Bg + (size_t)(n0 + ar0) * ldb + k0 + ao0 * 8, ldsB0);
    __syncthreads();
    short8 af[4];
#pragma unroll
    for (int mi = 0; mi < 4; ++mi) {
      int r = wm + mi * 16 + mr;
      af[mi] = *(const short8*)&Asub[r][(quad ^ (r & 3)) * 8];
    }
    short8 bfr[2];
#pragma unroll
    for (int ni = 0; ni < 2; ++ni) {
      int r = wn + ni * 16 + mr;
      bfr[ni] = *(const short8*)&Bsub[r][(quad ^ (r & 3)) * 8];
    }
#pragma unroll
    for (int mi = 0; mi < 4; ++mi)
#pragma unroll
      for (int ni = 0; ni < 2; ++ni)
        acc[mi][ni] = __builtin_amdgcn_mfma_f32_16x16x32_bf16(af[mi], bfr[ni], acc[mi][ni], 0, 0, 0);
    __syncthreads();
  }

  size_t cbase = (size_t)blockIdx.z * batchC;
#pragma unroll
  for (int mi = 0; mi < 4; ++mi) {
#pragma unroll
    for (int ni = 0; ni < 2; ++ni) {
#pragma unroll
      for (int r = 0; r < 4; ++r) {
        int gm = m0 + wm + mi * 16 + quad * 4 + r;
        int gn = n0 + wn + ni * 16 + mr;
        float v = acc[mi][ni][r];
        if (mode == 0) {
          ((float*)C)[cbase + (size_t)gm * ldc + gn] = v;
        } else if (mode == 1) {
          ((bf16*)C)[cbase + (size_t)gm * ldc + gn] = f2b(v);
        } else if (mode == 2) {
          int kk = gn - 512 + gm;
          if (kk >= 0 && kk < 512) {
            bf16* Cb = (bf16*)C;
            size_t idx = (size_t)blockIdx.z * NPAIR + (size_t)gm * 512 + kk;
            float corr = extra[blockIdx.z * PEROWS + gn];
            Cb[idx] = f2b(b2f(Cb[idx]) + 0.5f * (v + corr));
          }
        } else {  // mode 3
          int kk = gn - 512 + gm;
          if (kk >= 0 && kk < 512) {
            bf16* Cb = (bf16*)C;
            size_t idx = (size_t)blockIdx.z * NPAIR + (size_t)gm * 512 + kk;
            float corr = extra[blockIdx.z * PEROWS + gn];
            Cb[idx] = f2b(0.5f * (v + corr));
          }
        }
      }
    }
  }
}

// ---------------------------------------------------------------------------
// K6a: SD[h][q][k] += SDT[h][k][q]  (coalesced LDS-tiled transpose-add)
// ---------------------------------------------------------------------------
__global__ __launch_bounds__(256) void add_transpose(
    const bf16* __restrict__ SDT, bf16* __restrict__ SD) {
  __shared__ short tile[32][36];  // pad to break bank alignment
  int h = blockIdx.z;
  int k0 = blockIdx.x * 32, q0 = blockIdx.y * 32;
  int r = threadIdx.x >> 3;        // 0..31
  int c = (threadIdx.x & 7) * 4;   // 0,4,...,28
  const short* src = (const short*)SDT + (size_t)h * NPAIR;
  short* dst = (short*)SD + (size_t)h * NPAIR;
  short4v v = *(const short4v*)&src[(size_t)(k0 + r) * 512 + q0 + c];
#pragma unroll
  for (int j = 0; j < 4; ++j) tile[r][c + j] = v[j];
  __syncthreads();
  size_t didx = (size_t)(q0 + r) * 512 + k0 + c;
  short4v d = *(const short4v*)&dst[didx];
#pragma unroll
  for (int j = 0; j < 4; ++j) {
    short a = d[j];
    short b = tile[c + j][r];
    d[j] = f2bs(bs2f(a) + bs2f(b));
  }
  *(short4v*)&dst[didx] = d;
}

// ---------------------------------------------------------------------------
// K6b: pack -> P[(q*512+k)][h] (bf16, h contiguous). Pure coalesced gather.
// ---------------------------------------------------------------------------
__global__ __launch_bounds__(256) void combine_pack(
    const bf16* __restrict__ SD, bf16* __restrict__ P) {
  int q = blockIdx.x;
  int k = blockIdx.y * 256 + threadIdx.x;
  bf16* Pout = P + ((size_t)q * 512 + k) * 32;
#pragma unroll
  for (int h8 = 0; h8 < 4; ++h8) {
    short8 pack;
#pragma unroll
    for (int j = 0; j < 8; ++j) {
      int h = h8 * 8 + j;
      pack[j] = *(const short*)&SD[((size_t)(h * 512 + q)) * 512 + k];
    }
    *(short8*)(Pout + h8 * 8) = pack;
  }
}

// ---------------------------------------------------------------------------
// K7: pair projection MFMA:  out[m][c] = P[m][:32] @ W_pair[:32][c] + b_pair[c]
//                                        + yqk[q][c] + yqk[k][128+c]
// ---------------------------------------------------------------------------
__global__ __launch_bounds__(256) void pair_gemm(
    const bf16* __restrict__ P, const bf16* __restrict__ WpT,
    const float* __restrict__ b_pair, const float* __restrict__ yqk,
    float* __restrict__ out) {
  int t = threadIdx.x, lane = t & 63, w = t >> 6;
  int quad = lane >> 4, mr = lane & 15;
  int m0 = blockIdx.x * 128;
  int wm = w * 32;
  int q = m0 >> 9;  // constant per block (128 | 512)

  short8 af[2];
#pragma unroll
  for (int mi = 0; mi < 2; ++mi) {
    int m = m0 + wm + mi * 16 + mr;
    af[mi] = *(const short8*)(P + (size_t)m * 32 + quad * 8);
  }

  f32x4 acc[2][8];
#pragma unroll
  for (int mi = 0; mi < 2; ++mi)
#pragma unroll
    for (int ni = 0; ni < 8; ++ni) acc[mi][ni] = (f32x4){0.f, 0.f, 0.f, 0.f};

  float bqv[8];
#pragma unroll
  for (int ni = 0; ni < 8; ++ni) {
    int c = ni * 16 + mr;
    bqv[ni] = b_pair[c] + yqk[(size_t)q * 256 + c];
    short8 bfr = *(const short8*)(WpT + (size_t)c * 32 + quad * 8);
#pragma unroll
    for (int mi = 0; mi < 2; ++mi)
      acc[mi][ni] = __builtin_amdgcn_mfma_f32_16x16x32_bf16(af[mi], bfr, acc[mi][ni], 0, 0, 0);
  }

#pragma unroll
  for (int mi = 0; mi < 2; ++mi) {
#pragma unroll
    for (int r = 0; r < 4; ++r) {
      int m_out = m0 + wm + mi * 16 + quad * 4 + r;
      int k = m_out & 511;
      const float* ykrow = yqk + (size_t)k * 256 + 128;
#pragma unroll
      for (int ni = 0; ni < 8; ++ni) {
        int c = ni * 16 + mr;
        out[(size_t)m_out * HDIM + c] = acc[mi][ni][r] + bqv[ni] + ykrow[c];
      }
    }
  }
}

// ===========================================================================
extern "C" void kernel_launch(void* const* d_in, const int* in_sizes, int n_in,
                              void* d_out, int out_size, void* d_ws, size_t ws_size,
                              hipStream_t stream) {
  const float* x      = (const float*)d_in[0];
  const float* w_rms  = (const float*)d_in[1];
  const float* W_q    = (const float*)d_in[2];
  const float* W_k    = (const float*)d_in[3];
  const float* W_pos  = (const float*)d_in[4];
  const float* b_pos  = (const float*)d_in[5];
  const float* qrb    = (const float*)d_in[6];
  const float* krb    = (const float*)d_in[7];
  const float* W_yq   = (const float*)d_in[8];
  const float* W_yk   = (const float*)d_in[9];
  const float* W_pair = (const float*)d_in[10];
  const float* b_pair = (const float*)d_in[11];
  float* out = (float*)d_out;

  // ---- workspace layout (~82 MB) ----
  char* w = (char*)d_ws;
  bf16* xn   = (bf16*)w; w += (size_t)SPOOL * DMODEL * 2;       // 1.5 MB
  bf16* xg   = (bf16*)w; w += (size_t)SPOOL * DMODEL * 2;       // 1.5 MB
  bf16* pe   = (bf16*)w; w += (size_t)PEROWS * HDTOT * 2;       // 8.4 MB
  bf16* QKp  = (bf16*)w; w += (size_t)SPOOL * 8192 * 2;         // 8.4 MB (Q|K, row stride 8192)
  float* yqk = (float*)w; w += (size_t)SPOOL * 256 * 4;         // 0.5 MB
  bf16* yqkT = (bf16*)w; w += (size_t)256 * DMODEL * 2;         // 0.8 MB
  bf16* WpT  = (bf16*)w; w += (size_t)HDIM * NHEADS * 2;        // 8 KB
  float* SW0 = (float*)w; w += (size_t)33 * HDTOT * 4;          // 0.54 MB
  float* SW1 = (float*)w; w += (size_t)33 * HDTOT * 4;          // 0.54 MB
  float* cq  = (float*)w; w += (size_t)NHEADS * PEROWS * 4;     // 0.13 MB
  float* ck  = (float*)w; w += (size_t)NHEADS * PEROWS * 4;     // 0.13 MB
  // union region: {WqT, WkT} live only until projections; SDT written after.
  char* uni = w;
  bf16* WqT = (bf16*)uni;
  bf16* WkT = (bf16*)(uni + (size_t)HDTOT * DMODEL * 2);        // adjacent: N=8192 concat
  bf16* SDT = (bf16*)uni;                                       // 16.8 MB
  w = uni + (size_t)2 * HDTOT * DMODEL * 2;                     // 25.2 MB union
  bf16* SD  = (bf16*)w; w += (size_t)NHEADS * NPAIR * 2;        // 16.8 MB
  bf16* P   = (bf16*)w; w += (size_t)NPAIR * NHEADS * 2;        // 16.8 MB

  bf16* Qp = QKp;           // columns [0,4096),    lda=8192
  bf16* Kp = QKp + HDTOT;   // columns [4096,8192), lda=8192

  // 1. pool + rms + gelu
  pool_rms_gelu_bf<<<SPOOL, 256, 0, stream>>>(x, w_rms, xn, xg);
  // 2. pos-enc via suffix sums
  suffix_kernel<<<HDTOT / 256, 256, 0, stream>>>(W_pos, SW0, SW1);
  pos_enc2<<<PEROWS, 256, 0, stream>>>(SW0, SW1, b_pos, pe);
  // 3. weight transposes (bf16, K-contiguous)
  transpose_cast<<<dim3(HDTOT / 32, DMODEL / 32), 256, 0, stream>>>(W_q, WqT, DMODEL, HDTOT);
  transpose_cast<<<dim3(HDTOT / 32, DMODEL / 32), 256, 0, stream>>>(W_k, WkT, DMODEL, HDTOT);
  transpose_cast<<<dim3(HDIM / 32, DMODEL / 32), 256, 0, stream>>>(W_yq, yqkT, DMODEL, HDIM);
  transpose_cast<<<dim3(HDIM / 32, DMODEL / 32), 256, 0, stream>>>(W_yk, yqkT + (size_t)HDIM * DMODEL, DMODEL, HDIM);
  transpose_cast<<<dim3(HDIM / 32, 1), 256, 0, stream>>>(W_pair, WpT, NHEADS, HDIM);
  // 4. rank-1 bias corrections
  cqck_kernel<<<dim3(NHEADS, 8), 256, 0, stream>>>(qrb, krb, pe, cq, ck);
  // 5. Q|K projection in ONE GEMM (WqT/WkT adjacent -> N=8192), bf16 out
  gemm_mfma<<<dim3(8192 / 64, SPOOL / 128, 1), 256, 0, stream>>>(
      xn, DMODEL, 0, WqT, DMODEL, 0, QKp, 8192, 0, nullptr, 1, SPOOL, 8192, DMODEL);
  // 6. yq|yk (fp32 out)
  gemm_mfma<<<dim3(256 / 64, SPOOL / 128, 1), 256, 0, stream>>>(
      xg, DMODEL, 0, yqkT, DMODEL, 0, yqk, 256, 0, nullptr, 0, SPOOL, 256, DMODEL);
  // 7. S[h][q][k] = Q_h . K_h^T  (bf16)
  gemm_mfma<<<dim3(SPOOL / 64, SPOOL / 128, NHEADS), 256, 0, stream>>>(
      Qp, 8192, HDIM, Kp, 8192, HDIM, SD, 512, NPAIR, nullptr, 1, SPOOL, SPOOL, HDIM);
  // 8. Dq: SD[h][q][k=p-512+q] += 0.5*(Q.pe^T + cq)  (diag remap, band-trimmed)
  gemm_mfma<<<dim3(PEROWS / 64, SPOOL / 128, NHEADS), 256, 0, stream>>>(
      Qp, 8192, HDIM, pe, HDTOT, HDIM, SD, 512, NPAIR, cq, 2, SPOOL, PEROWS, HDIM);
  // 9. Gk-term: SDT[h][k][q] = 0.5*(K.pe^T + ck)  (diag remap, band-trimmed,
  //    coalesced stores; replaces full Gk materialization + scattered gather)
  gemm_mfma<<<dim3(PEROWS / 64, SPOOL / 128, NHEADS), 256, 0, stream>>>(
      Kp, 8192, HDIM, pe, HDTOT, HDIM, SDT, 512, NPAIR, ck, 3, SPOOL, PEROWS, HDIM);
  // 9b. SD += SDT^T  (LDS-tiled, fully coalesced)
  add_transpose<<<dim3(SPOOL / 32, SPOOL / 32, NHEADS), 256, 0, stream>>>(SDT, SD);
  // 10. pack -> P[(qk)][h]
  combine_pack<<<dim3(SPOOL, 2), 256, 0, stream>>>(SD, P);
  // 11. pair projection + epilogue
  pair_gemm<<<NPAIR / 128, 256, 0, stream>>>(P, WpT, b_pair, yqk, out);
}

// Round 3
// 402.763 us; speedup vs baseline: 1.2753x; 1.1639x over previous
//
#include <hip/hip_runtime.h>
#include <hip/hip_bf16.h>
#include <math.h>
#include <stdint.h>

#define NHEADS 32
#define HDIM 128
#define POOLW 16
#define DMODEL 1536
#define SPOOL 512
#define HDTOT 4096   // NHEADS*HDIM
#define PEROWS 1024  // 2*SPOOL
#define NPAIR (SPOOL * SPOOL)   // 262144
#define TCOLS 80     // padded table width (67 used)

typedef __hip_bfloat16 bf16;
typedef short short8 __attribute__((ext_vector_type(8)));
typedef float f32x4 __attribute__((ext_vector_type(4)));

__device__ __forceinline__ float b2f(const bf16 v) { return __bfloat162float(v); }
__device__ __forceinline__ bf16 f2b(float v) { return __float2bfloat16(v); }
__device__ __forceinline__ short f2bs(float v) {
  bf16 b = __float2bfloat16(v);
  return *reinterpret_cast<short*>(&b);
}

__device__ __forceinline__ void gload_lds16(const void* g, void* l) {
  const __attribute__((address_space(1))) uint32_t* gp =
      (const __attribute__((address_space(1))) uint32_t*)(uintptr_t)g;
  __attribute__((address_space(3))) uint32_t* lp =
      (__attribute__((address_space(3))) uint32_t*)(uintptr_t)l;
  __builtin_amdgcn_global_load_lds(gp, lp, 16, 0, 0);
}

// ---------------------------------------------------------------------------
// K1: pool (mean 16) + RMSNorm + GELU -> bf16 xn, xg
// ---------------------------------------------------------------------------
__global__ __launch_bounds__(256) void pool_rms_gelu_bf(
    const float* __restrict__ x, const float* __restrict__ w_rms,
    bf16* __restrict__ xn, bf16* __restrict__ xg) {
  int sp = blockIdx.x;
  int tid = threadIdx.x;
  __shared__ float buf[DMODEL];
  __shared__ float red[256];
  const float* xrow = x + (size_t)sp * POOLW * DMODEL;
  float ss = 0.f;
  for (int d = tid; d < DMODEL; d += 256) {
    float s = 0.f;
#pragma unroll
    for (int p = 0; p < POOLW; ++p) s += xrow[p * DMODEL + d];
    s *= (1.0f / POOLW);
    buf[d] = s;
    ss += s * s;
  }
  red[tid] = ss;
  __syncthreads();
  for (int off = 128; off > 0; off >>= 1) {
    if (tid < off) red[tid] += red[tid + off];
    __syncthreads();
  }
  float rms = rsqrtf(red[0] / DMODEL + 1e-6f);
  for (int d = tid; d < DMODEL; d += 256) {
    float v = buf[d] * rms * w_rms[d];
    xn[(size_t)sp * DMODEL + d] = f2b(v);
    xg[(size_t)sp * DMODEL + d] = f2b(0.5f * v * (1.0f + erff(v * 0.70710678118654752f)));
  }
}

// ---------------------------------------------------------------------------
// K2: suffix sums of W_pos rows. SW0[g][j] = sum_{f>=g} W_pos[f][j] (g=0..32)
// ---------------------------------------------------------------------------
__global__ __launch_bounds__(256) void suffix_kernel(
    const float* __restrict__ W_pos, float* __restrict__ SW0, float* __restrict__ SW1) {
  int j = blockIdx.x * 256 + threadIdx.x;
  float s0 = 0.f, s1 = 0.f;
  SW0[32 * HDTOT + j] = 0.f;
  SW1[32 * HDTOT + j] = 0.f;
  for (int f = 31; f >= 0; --f) {
    s0 += W_pos[f * HDTOT + j];
    s1 += W_pos[(NHEADS + f) * HDTOT + j];
    SW0[f * HDTOT + j] = s0;
    SW1[f * HDTOT + j] = s1;
  }
}

// ---------------------------------------------------------------------------
// K2b: prep. blocks 0..31: SWb[h][g][c] bf16 (g<33:SW0, 33..65:SW1, 66:b_pos, pad 0)
//      blocks 32..95: RB[s*32+h][g] = rbias . SWcat  (g>=67 -> 0)
//      block 96: fm table (1024 entries)
// ---------------------------------------------------------------------------
__global__ __launch_bounds__(256) void prep_kernel(
    const float* __restrict__ SW0, const float* __restrict__ SW1,
    const float* __restrict__ b_pos, const float* __restrict__ qrb,
    const float* __restrict__ krb, bf16* __restrict__ SWb,
    float* __restrict__ RB, short* __restrict__ fm_tab) {
  int b = blockIdx.x, t = threadIdx.x;
  if (b < 32) {
    int h = b;
    bf16* dst = SWb + (size_t)h * 128 * 128;
    for (int rr = 0; rr < 128; rr += 2) {
      int g = rr + (t >> 7);
      int c = t & 127;
      float v;
      if (g < 33) v = SW0[(size_t)g * HDTOT + h * 128 + c];
      else if (g < 66) v = SW1[(size_t)(g - 33) * HDTOT + h * 128 + c];
      else if (g == 66) v = b_pos[h * 128 + c];
      else v = 0.f;
      dst[(size_t)g * 128 + c] = f2b(v);
    }
  } else if (b < 96) {
    int idx = b - 32;           // s*32 + h
    int s = idx >> 5, h = idx & 31;
    const float* rb = (s ? krb : qrb) + h * 128;
    if (t < 128) {
      int g = t;
      float acc = 0.f;
      if (g < 33) { for (int c = 0; c < 128; ++c) acc += rb[c] * SW0[(size_t)g * HDTOT + h * 128 + c]; }
      else if (g < 66) { for (int c = 0; c < 128; ++c) acc += rb[c] * SW1[(size_t)(g - 33) * HDTOT + h * 128 + c]; }
      else if (g == 66) { for (int c = 0; c < 128; ++c) acc += rb[c] * b_pos[h * 128 + c]; }
      RB[(size_t)idx * 128 + g] = acc;
    }
  } else {
    for (int p = t; p < 1024; p += 256) {
      float dist = fabsf((float)(p - 512));
      double ls = log(481.0) / 32.0;  // log(512-32+1)/32
      int fmv = 0;
      for (int f = 0; f < 32; ++f) {
        float cw = (float)f + expf((float)f * (float)ls);
        if (cw <= dist) fmv = f + 1;
      }
      fm_tab[p] = (short)fmv;
    }
  }
}

// ---------------------------------------------------------------------------
// K3: transpose + cast  in[R][C] fp32 -> out[C][R] bf16
// ---------------------------------------------------------------------------
__global__ __launch_bounds__(256) void transpose_cast(
    const float* __restrict__ in, bf16* __restrict__ out, int R, int C) {
  __shared__ float tile[32][33];
  int c0 = blockIdx.x * 32, r0 = blockIdx.y * 32;
  int tx = threadIdx.x & 31, ty = threadIdx.x >> 5;
  for (int i = ty; i < 32; i += 8) tile[i][tx] = in[(size_t)(r0 + i) * C + c0 + tx];
  __syncthreads();
  for (int i = ty; i < 32; i += 8) out[(size_t)(c0 + i) * R + r0 + tx] = f2b(tile[tx][i]);
}

// ---------------------------------------------------------------------------
// K5: bf16 MFMA GEMM:  C[M][N] = A[M][K] @ BT[N][K]^T  (both K-contiguous)
// 128x64 tile, BK=32, 256 threads.
// mode 0: fp32 store; mode 1: bf16 store;
// mode 5: f32 store to ldc=TCOLS with extra[z*128+gn] add, only gn<TCOLS.
// ---------------------------------------------------------------------------
__global__ __launch_bounds__(256) void gemm_mfma(
    const bf16* __restrict__ A, int lda, long long batchA,
    const bf16* __restrict__ BT, int ldb, long long batchB,
    void* __restrict__ C, int ldc, long long batchC,
    const float* __restrict__ extra, int mode, int M, int N, int K) {
  __shared__ short Asub[128][32];
  __shared__ short Bsub[64][32];
  const int t = threadIdx.x;
  const int lane = t & 63;
  const int w = t >> 6;
  const int m0 = blockIdx.y * 128, n0 = blockIdx.x * 64;
  const int wm = (w >> 1) * 64, wn = (w & 1) * 32;
  const bf16* Ag = A + (size_t)blockIdx.z * batchA;
  const bf16* Bg = BT + (size_t)blockIdx.z * batchB;

  const int ar0 = t >> 2;
  const int as0 = t & 3;
  const int ao0 = as0 ^ (ar0 & 3);
  char* AsubB = (char*)&Asub[0][0];
  char* BsubB = (char*)&Bsub[0][0];
  char* ldsA0 = AsubB + w * 1024;
  char* ldsA1 = AsubB + 4096 + w * 1024;
  char* ldsB0 = BsubB + w * 1024;

  const int quad = lane >> 4, mr = lane & 15;
  f32x4 acc[4][2];
#pragma unroll
  for (int mi = 0; mi < 4; ++mi)
#pragma unroll
    for (int ni = 0; ni < 2; ++ni) acc[mi][ni] = (f32x4){0.f, 0.f, 0.f, 0.f};

  for (int k0 = 0; k0 < K; k0 += 32) {
    gload_lds16(Ag + (size_t)(m0 + ar0) * lda + k0 + ao0 * 8, ldsA0);
    gload_lds16(Ag + (size_t)(m0 + 64 + ar0) * lda + k0 + ao0 * 8, ldsA1);
    gload_lds16(Bg + (size_t)(n0 + ar0) * ldb + k0 + ao0 * 8, ldsB0);
    __syncthreads();
    short8 af[4];
#pragma unroll
    for (int mi = 0; mi < 4; ++mi) {
      int r = wm + mi * 16 + mr;
      af[mi] = *(const short8*)&Asub[r][(quad ^ (r & 3)) * 8];
    }
    short8 bfr[2];
#pragma unroll
    for (int ni = 0; ni < 2; ++ni) {
      int r = wn + ni * 16 + mr;
      bfr[ni] = *(const short8*)&Bsub[r][(quad ^ (r & 3)) * 8];
    }
#pragma unroll
    for (int mi = 0; mi < 4; ++mi)
#pragma unroll
      for (int ni = 0; ni < 2; ++ni)
        acc[mi][ni] = __builtin_amdgcn_mfma_f32_16x16x32_bf16(af[mi], bfr[ni], acc[mi][ni], 0, 0, 0);
    __syncthreads();
  }

  size_t cbase = (size_t)blockIdx.z * batchC;
#pragma unroll
  for (int mi = 0; mi < 4; ++mi) {
#pragma unroll
    for (int ni = 0; ni < 2; ++ni) {
#pragma unroll
      for (int r = 0; r < 4; ++r) {
        int gm = m0 + wm + mi * 16 + quad * 4 + r;
        int gn = n0 + wn + ni * 16 + mr;
        float v = acc[mi][ni][r];
        if (mode == 0) {
          ((float*)C)[cbase + (size_t)gm * ldc + gn] = v;
        } else if (mode == 1) {
          ((bf16*)C)[cbase + (size_t)gm * ldc + gn] = f2b(v);
        } else {  // mode 5: table store with rank-1 bias fold
          if (gn < TCOLS) {
            ((float*)C)[cbase + (size_t)gm * ldc + gn] =
                v + extra[blockIdx.z * 128 + gn];
          }
        }
      }
    }
  }
}

// ---------------------------------------------------------------------------
// MEGA: per 32x32 (q,k) tile, loop h: S=Q_h.K_h^T (MFMA) + table-lookup rel
// terms -> P[m][h] in LDS; then pair projection + epilogue -> out.
// 512 threads. LDS (bytes):
//   Qs [4][32][32]s @0       Ks @8192
//   Tq dbuf @16384/+10240    Tk dbuf @36864/+10240   (each 32 rows x 80 f32)
//   Ssc [32][33]f @57344     fmL [1024]s @61568   Pl [1024][40]s @63616
// total 145536
// ---------------------------------------------------------------------------
#define MEGA_LDS 145536
__global__ __launch_bounds__(512) void mega_kernel(
    const bf16* __restrict__ QKp, const float* __restrict__ Tg,
    const short* __restrict__ fm_tab, const bf16* __restrict__ WpT,
    const float* __restrict__ b_pair, const float* __restrict__ yqk,
    float* __restrict__ out) {
  extern __shared__ char sm[];
  short* Qs = (short*)(sm);
  short* Ks = (short*)(sm + 8192);
  float* Ssc = (float*)(sm + 57344);
  short* fmL = (short*)(sm + 61568);
  short* Pl = (short*)(sm + 63616);

  const int t = threadIdx.x;
  const int lane = t & 63, w = t >> 6;
  const int quad = lane >> 4, mr = lane & 15;
  const int q0 = (blockIdx.x >> 4) * 32;
  const int k0 = (blockIdx.x & 15) * 32;

  // ---- staging helpers ----
  // Qs/Ks: k-step-slab layout [ks][r][32] with chunk swizzle pc^(r&3)
  const int c_ks = t >> 7;
  const int c_cc = t & 127;
  const int c_r = c_cc >> 2;
  const int c_pc = c_cc & 3;
  const int qk_col = c_ks * 32 + ((c_pc ^ (c_r & 3)) * 8);
  // T staging: 640 chunks/side, linear rows of 80 f32
  const int t_r0 = t / 20, t_p0 = t - t_r0 * 20;
  const int c2 = 512 + t;
  const int t_r1 = c2 / 20, t_p1 = c2 - t_r1 * 20;

#define STAGE_QK(h)                                                                   \
  {                                                                                   \
    gload_lds16(QKp + (size_t)(q0 + c_r) * 8192 + (h)*128 + qk_col, (char*)Qs + t * 16); \
    gload_lds16(QKp + (size_t)(k0 + c_r) * 8192 + 4096 + (h)*128 + qk_col,            \
                (char*)Ks + t * 16);                                                  \
  }
#define STAGE_T(h)                                                                    \
  {                                                                                   \
    char* dq = sm + 16384 + ((h)&1) * 10240;                                          \
    char* dk = sm + 36864 + ((h)&1) * 10240;                                          \
    const float* sq_ = Tg + (size_t)(h)*512 * TCOLS;                                  \
    const float* sk_ = Tg + (size_t)(32 + (h)) * 512 * TCOLS;                         \
    gload_lds16(sq_ + (size_t)(q0 + t_r0) * TCOLS + t_p0 * 4, dq + t * 16);           \
    gload_lds16(sk_ + (size_t)(k0 + t_r0) * TCOLS + t_p0 * 4, dk + t * 16);           \
    if (t < 128) {                                                                    \
      gload_lds16(sq_ + (size_t)(q0 + t_r1) * TCOLS + t_p1 * 4, dq + c2 * 16);        \
      gload_lds16(sk_ + (size_t)(k0 + t_r1) * TCOLS + t_p1 * 4, dk + c2 * 16);        \
    }                                                                                 \
  }

  // prologue
  if (t < 128) gload_lds16(fm_tab + t * 8, (char*)fmL + t * 16);
  STAGE_QK(0);
  STAGE_T(0);
  __syncthreads();

  for (int h = 0; h < 32; ++h) {
    // ---- compute S (waves 0..3) ----
    if (w < 4) {
      const int smi = w >> 1, sni = w & 1;
      const int ra = smi * 16 + mr, rb = sni * 16 + mr;
      f32x4 accS = (f32x4){0.f, 0.f, 0.f, 0.f};
#pragma unroll
      for (int ks = 0; ks < 4; ++ks) {
        short8 af = *(const short8*)&Qs[ks * 1024 + ra * 32 + ((quad ^ (ra & 3)) * 8)];
        short8 bfv = *(const short8*)&Ks[ks * 1024 + rb * 32 + ((quad ^ (rb & 3)) * 8)];
        accS = __builtin_amdgcn_mfma_f32_16x16x32_bf16(af, bfv, accS, 0, 0, 0);
      }
#pragma unroll
      for (int r = 0; r < 4; ++r)
        Ssc[(smi * 16 + quad * 4 + r) * 33 + sni * 16 + mr] = accS[r];
    }
    __syncthreads();
    if (h < 31) {
      STAGE_QK(h + 1);
      STAGE_T(h + 1);
    }
    // ---- pack column h of P ----
    {
      const float* tq = (const float*)(sm + 16384 + (h & 1) * 10240);
      const float* tk = (const float*)(sm + 36864 + (h & 1) * 10240);
#pragma unroll
      for (int j = 0; j < 2; ++j) {
        int m = j * 512 + t;
        int qL = m >> 5, kL = m & 31;
        int pq = 512 + (k0 + kL) - (q0 + qL);
        int gq = fmL[pq], gk = fmL[1024 - pq];
        float sq = (pq > 512) ? 1.f : ((pq < 512) ? -1.f : 0.f);
        float vq = tq[qL * TCOLS + gq] + sq * tq[qL * TCOLS + 33 + gq] + tq[qL * TCOLS + 66];
        float vk = tk[kL * TCOLS + gk] - sq * tk[kL * TCOLS + 33 + gk] + tk[kL * TCOLS + 66];
        float val = Ssc[qL * 33 + kL] + 0.5f * (vq + vk);
        Pl[m * 40 + h] = f2bs(val);
      }
    }
    __syncthreads();
  }

  // ---- pair projection + epilogue ----
  short8 bfr[8];
  float bp[8];
#pragma unroll
  for (int ni = 0; ni < 8; ++ni) {
    int c = ni * 16 + mr;
    bfr[ni] = *(const short8*)(WpT + (size_t)c * 32 + quad * 8);
    bp[ni] = b_pair[c];
  }
#pragma unroll
  for (int mi = 0; mi < 8; ++mi) {
    int mb = w * 128 + mi * 16;
    short8 af = *(const short8*)&Pl[(mb + mr) * 40 + quad * 8];
    f32x4 acc[8];
#pragma unroll
    for (int ni = 0; ni < 8; ++ni)
      acc[ni] = __builtin_amdgcn_mfma_f32_16x16x32_bf16(
          af, bfr[ni], (f32x4){0.f, 0.f, 0.f, 0.f}, 0, 0, 0);
#pragma unroll
    for (int r = 0; r < 4; ++r) {
      int m = mb + quad * 4 + r;
      int q = q0 + (m >> 5), k = k0 + (m & 31);
      const float* yq = yqk + (size_t)q * 256;
      const float* yk = yqk + (size_t)k * 256 + 128;
      float* orow = out + ((size_t)q * 512 + k) * 128;
#pragma unroll
      for (int ni = 0; ni < 8; ++ni) {
        int c = ni * 16 + mr;
        orow[c] = acc[ni][r] + bp[ni] + yq[c] + yk[c];
      }
    }
  }
}

// ===========================================================================
extern "C" void kernel_launch(void* const* d_in, const int* in_sizes, int n_in,
                              void* d_out, int out_size, void* d_ws, size_t ws_size,
                              hipStream_t stream) {
  const float* x      = (const float*)d_in[0];
  const float* w_rms  = (const float*)d_in[1];
  const float* W_q    = (const float*)d_in[2];
  const float* W_k    = (const float*)d_in[3];
  const float* W_pos  = (const float*)d_in[4];
  const float* b_pos  = (const float*)d_in[5];
  const float* qrb    = (const float*)d_in[6];
  const float* krb    = (const float*)d_in[7];
  const float* W_yq   = (const float*)d_in[8];
  const float* W_yk   = (const float*)d_in[9];
  const float* W_pair = (const float*)d_in[10];
  const float* b_pair = (const float*)d_in[11];
  float* out = (float*)d_out;

  static bool attr_set = false;
  if (!attr_set) {
    (void)hipFuncSetAttribute((const void*)mega_kernel,
                              hipFuncAttributeMaxDynamicSharedMemorySize, MEGA_LDS);
    attr_set = true;
  }

  // ---- workspace layout (~66 MB) ----
  char* w = (char*)d_ws;
  bf16* xn   = (bf16*)w; w += (size_t)SPOOL * DMODEL * 2;       // 1.5 MB
  bf16* xg   = (bf16*)w; w += (size_t)SPOOL * DMODEL * 2;       // 1.5 MB
  bf16* QKp  = (bf16*)w; w += (size_t)SPOOL * 8192 * 2;         // 8.4 MB (Q|K)
  float* yqk = (float*)w; w += (size_t)SPOOL * 256 * 4;         // 0.5 MB
  bf16* yqkT = (bf16*)w; w += (size_t)256 * DMODEL * 2;         // 0.8 MB
  bf16* WpT  = (bf16*)w; w += (size_t)HDIM * NHEADS * 2;        // 8 KB
  float* SW0 = (float*)w; w += (size_t)33 * HDTOT * 4;          // 0.54 MB
  float* SW1 = (float*)w; w += (size_t)33 * HDTOT * 4;          // 0.54 MB
  bf16* SWb  = (bf16*)w; w += (size_t)NHEADS * 128 * 128 * 2;   // 1.05 MB
  float* RB  = (float*)w; w += (size_t)64 * 128 * 4;            // 32 KB
  short* fm_tab = (short*)w; w += 1024 * 2;                     // 2 KB
  w = (char*)(((uintptr_t)w + 255) & ~(uintptr_t)255);
  bf16* WqT = (bf16*)w; w += (size_t)HDTOT * DMODEL * 2;        // 12.6 MB
  bf16* WkT = (bf16*)w; w += (size_t)HDTOT * DMODEL * 2;        // 12.6 MB
  float* Tg = (float*)w; w += (size_t)2 * NHEADS * SPOOL * TCOLS * 4;  // 26.2 MB

  // 1. pool + rms + gelu
  pool_rms_gelu_bf<<<SPOOL, 256, 0, stream>>>(x, w_rms, xn, xg);
  // 2. suffix sums + prep tables (SWb, RB, fm)
  suffix_kernel<<<HDTOT / 256, 256, 0, stream>>>(W_pos, SW0, SW1);
  prep_kernel<<<97, 256, 0, stream>>>(SW0, SW1, b_pos, qrb, krb, SWb, RB, fm_tab);
  // 3. weight transposes (bf16, K-contiguous)
  transpose_cast<<<dim3(HDTOT / 32, DMODEL / 32), 256, 0, stream>>>(W_q, WqT, DMODEL, HDTOT);
  transpose_cast<<<dim3(HDTOT / 32, DMODEL / 32), 256, 0, stream>>>(W_k, WkT, DMODEL, HDTOT);
  transpose_cast<<<dim3(HDIM / 32, DMODEL / 32), 256, 0, stream>>>(W_yq, yqkT, DMODEL, HDIM);
  transpose_cast<<<dim3(HDIM / 32, DMODEL / 32), 256, 0, stream>>>(W_yk, yqkT + (size_t)HDIM * DMODEL, DMODEL, HDIM);
  transpose_cast<<<dim3(HDIM / 32, 1), 256, 0, stream>>>(W_pair, WpT, NHEADS, HDIM);
  // 4. Q|K projection in ONE GEMM (WqT/WkT adjacent -> N=8192), bf16 out
  gemm_mfma<<<dim3(8192 / 64, SPOOL / 128, 1), 256, 0, stream>>>(
      xn, DMODEL, 0, WqT, DMODEL, 0, QKp, 8192, 0, nullptr, 1, SPOOL, 8192, DMODEL);
  // 5. yq|yk (fp32 out)
  gemm_mfma<<<dim3(256 / 64, SPOOL / 128, 1), 256, 0, stream>>>(
      xg, DMODEL, 0, yqkT, DMODEL, 0, yqk, 256, 0, nullptr, 0, SPOOL, 256, DMODEL);
  // 6. rel tables: T[side][h][q][g] = Q/K_h . SWcat_h^T + rbias fold (f32)
  gemm_mfma<<<dim3(128 / 64, SPOOL / 128, NHEADS), 256, 0, stream>>>(
      QKp, 8192, 128, SWb, 128, 128 * 128, Tg, TCOLS, (long long)SPOOL * TCOLS,
      RB, 5, SPOOL, 128, 128);
  gemm_mfma<<<dim3(128 / 64, SPOOL / 128, NHEADS), 256, 0, stream>>>(
      QKp + 4096, 8192, 128, SWb, 128, 128 * 128,
      Tg + (size_t)NHEADS * SPOOL * TCOLS, TCOLS, (long long)SPOOL * TCOLS,
      RB + 32 * 128, 5, SPOOL, 128, 128);
  // 7. fused S + rel-lookup + pack + pair projection + epilogue
  mega_kernel<<<256, 512, MEGA_LDS, stream>>>(QKp, Tg, fm_tab, WpT, b_pair, yqk, out);
}

// Round 4
// 344.456 us; speedup vs baseline: 1.4911x; 1.1693x over previous
//
#include <hip/hip_runtime.h>
#include <hip/hip_bf16.h>
#include <math.h>
#include <stdint.h>

#define NHEADS 32
#define HDIM 128
#define POOLW 16
#define DMODEL 1536
#define SPOOL 512
#define HDTOT 4096   // NHEADS*HDIM
#define PEROWS 1024  // 2*SPOOL
#define NPAIR (SPOOL * SPOOL)   // 262144
#define TCOLS 80     // padded table width (67 used)

typedef __hip_bfloat16 bf16;
typedef short short8 __attribute__((ext_vector_type(8)));
typedef float f32x4 __attribute__((ext_vector_type(4)));

__device__ __forceinline__ float b2f(const bf16 v) { return __bfloat162float(v); }
__device__ __forceinline__ bf16 f2b(float v) { return __float2bfloat16(v); }
__device__ __forceinline__ short f2bs(float v) {
  bf16 b = __float2bfloat16(v);
  return *reinterpret_cast<short*>(&b);
}

__device__ __forceinline__ void gload_lds16(const void* g, void* l) {
  const __attribute__((address_space(1))) uint32_t* gp =
      (const __attribute__((address_space(1))) uint32_t*)(uintptr_t)g;
  __attribute__((address_space(3))) uint32_t* lp =
      (__attribute__((address_space(3))) uint32_t*)(uintptr_t)l;
  __builtin_amdgcn_global_load_lds(gp, lp, 16, 0, 0);
}

// ---------------------------------------------------------------------------
// K1: pool (mean 16) + RMSNorm + GELU -> bf16 xn, xg
// ---------------------------------------------------------------------------
__global__ __launch_bounds__(256) void pool_rms_gelu_bf(
    const float* __restrict__ x, const float* __restrict__ w_rms,
    bf16* __restrict__ xn, bf16* __restrict__ xg) {
  int sp = blockIdx.x;
  int tid = threadIdx.x;
  __shared__ float buf[DMODEL];
  __shared__ float red[256];
  const float* xrow = x + (size_t)sp * POOLW * DMODEL;
  float ss = 0.f;
  for (int d = tid; d < DMODEL; d += 256) {
    float s = 0.f;
#pragma unroll
    for (int p = 0; p < POOLW; ++p) s += xrow[p * DMODEL + d];
    s *= (1.0f / POOLW);
    buf[d] = s;
    ss += s * s;
  }
  red[tid] = ss;
  __syncthreads();
  for (int off = 128; off > 0; off >>= 1) {
    if (tid < off) red[tid] += red[tid + off];
    __syncthreads();
  }
  float rms = rsqrtf(red[0] / DMODEL + 1e-6f);
  for (int d = tid; d < DMODEL; d += 256) {
    float v = buf[d] * rms * w_rms[d];
    xn[(size_t)sp * DMODEL + d] = f2b(v);
    xg[(size_t)sp * DMODEL + d] = f2b(0.5f * v * (1.0f + erff(v * 0.70710678118654752f)));
  }
}

// ---------------------------------------------------------------------------
// K2: suffix sums of W_pos rows. SW0[g][j] = sum_{f>=g} W_pos[f][j] (g=0..32)
// ---------------------------------------------------------------------------
__global__ __launch_bounds__(256) void suffix_kernel(
    const float* __restrict__ W_pos, float* __restrict__ SW0, float* __restrict__ SW1) {
  int j = blockIdx.x * 256 + threadIdx.x;
  float s0 = 0.f, s1 = 0.f;
  SW0[32 * HDTOT + j] = 0.f;
  SW1[32 * HDTOT + j] = 0.f;
  for (int f = 31; f >= 0; --f) {
    s0 += W_pos[f * HDTOT + j];
    s1 += W_pos[(NHEADS + f) * HDTOT + j];
    SW0[f * HDTOT + j] = s0;
    SW1[f * HDTOT + j] = s1;
  }
}

// ---------------------------------------------------------------------------
// K2b: prep. blocks 0..31: SWb[h][g][c] bf16 (g<33:SW0, 33..65:SW1, 66:b_pos, pad 0)
//      blocks 32..95: RB[s*32+h][g] = rbias . SWcat  (g>=67 -> 0)
//      block 96: fm table (1024 entries); block 97: WpT transpose
// ---------------------------------------------------------------------------
__global__ __launch_bounds__(256) void prep_kernel(
    const float* __restrict__ SW0, const float* __restrict__ SW1,
    const float* __restrict__ b_pos, const float* __restrict__ qrb,
    const float* __restrict__ krb, const float* __restrict__ W_pair,
    bf16* __restrict__ SWb, float* __restrict__ RB, short* __restrict__ fm_tab,
    bf16* __restrict__ WpT) {
  int b = blockIdx.x, t = threadIdx.x;
  if (b < 32) {
    int h = b;
    bf16* dst = SWb + (size_t)h * 128 * 128;
    for (int rr = 0; rr < 128; rr += 2) {
      int g = rr + (t >> 7);
      int c = t & 127;
      float v;
      if (g < 33) v = SW0[(size_t)g * HDTOT + h * 128 + c];
      else if (g < 66) v = SW1[(size_t)(g - 33) * HDTOT + h * 128 + c];
      else if (g == 66) v = b_pos[h * 128 + c];
      else v = 0.f;
      dst[(size_t)g * 128 + c] = f2b(v);
    }
  } else if (b < 96) {
    int idx = b - 32;           // s*32 + h
    int s = idx >> 5, h = idx & 31;
    const float* rb = (s ? krb : qrb) + h * 128;
    if (t < 128) {
      int g = t;
      float acc = 0.f;
      if (g < 33) { for (int c = 0; c < 128; ++c) acc += rb[c] * SW0[(size_t)g * HDTOT + h * 128 + c]; }
      else if (g < 66) { for (int c = 0; c < 128; ++c) acc += rb[c] * SW1[(size_t)(g - 33) * HDTOT + h * 128 + c]; }
      else if (g == 66) { for (int c = 0; c < 128; ++c) acc += rb[c] * b_pos[h * 128 + c]; }
      RB[(size_t)idx * 128 + g] = acc;
    }
  } else if (b == 96) {
    for (int p = t; p < 1024; p += 256) {
      float dist = fabsf((float)(p - 512));
      double ls = log(481.0) / 32.0;  // log(512-32+1)/32
      int fmv = 0;
      for (int f = 0; f < 32; ++f) {
        float cw = (float)f + expf((float)f * (float)ls);
        if (cw <= dist) fmv = f + 1;
      }
      fm_tab[p] = (short)fmv;
    }
  } else {
    // WpT[c][h] = W_pair[h][c]
    for (int idx = t; idx < NHEADS * HDIM; idx += 256) {
      int c = idx >> 5, h = idx & 31;
      WpT[(size_t)c * 32 + h] = f2b(W_pair[h * HDIM + c]);
    }
  }
}

// ---------------------------------------------------------------------------
// K5a: projection GEMM reading W directly in f32 [K][N] layout.
//  blockIdx.x < 128 : C=QKp bf16, A=xn, W = W_q (x<64) | W_k, ldw=4096
//  blockIdx.x >= 128: C=yqk f32,  A=xg, W = W_yq (x=128,129) | W_yk, ldw=128
// 128x64 tile, BK=32, 256 threads. A via global_load_lds (bf16, xor swizzle);
// B reg-staged f32->bf16 into Bsub[64][40] (pad 40: 16B-aligned rows, even banks).
// ---------------------------------------------------------------------------
__global__ __launch_bounds__(256) void gemm_proj(
    const bf16* __restrict__ xn, const bf16* __restrict__ xg,
    const float* __restrict__ W_q, const float* __restrict__ W_k,
    const float* __restrict__ W_yq, const float* __restrict__ W_yk,
    bf16* __restrict__ QKp, float* __restrict__ yqk) {
  __shared__ short Asub[128][32];
  __shared__ short Bsub[64][40];
  const int t = threadIdx.x;
  const int lane = t & 63;
  const int w = t >> 6;
  const int bx = blockIdx.x;
  const int m0 = blockIdx.y * 128;
  const int wm = (w >> 1) * 64, wn = (w & 1) * 32;

  const bf16* A;
  const float* Wb;
  int ncol, ldw;
  if (bx < 128) {
    A = xn;
    int n0 = bx * 64;
    if (n0 < 4096) { Wb = W_q; ncol = n0; } else { Wb = W_k; ncol = n0 - 4096; }
    ldw = 4096;
  } else {
    A = xg;
    int x2 = bx - 128;
    int n0 = x2 * 64;
    if (n0 < 128) { Wb = W_yq; ncol = n0; } else { Wb = W_yk; ncol = n0 - 128; }
    ldw = 128;
  }

  const int ar0 = t >> 2;
  const int as0 = t & 3;
  const int ao0 = as0 ^ (ar0 & 3);
  char* AsubB = (char*)&Asub[0][0];
  char* ldsA0 = AsubB + w * 1024;
  char* ldsA1 = AsubB + 4096 + w * 1024;

  const int bn = t & 63;   // B stage: n within tile
  const int bkg = t >> 6;  // k-group of 8

  const int quad = lane >> 4, mr = lane & 15;
  f32x4 acc[4][2];
#pragma unroll
  for (int mi = 0; mi < 4; ++mi)
#pragma unroll
    for (int ni = 0; ni < 2; ++ni) acc[mi][ni] = (f32x4){0.f, 0.f, 0.f, 0.f};

  for (int k0 = 0; k0 < DMODEL; k0 += 32) {
    gload_lds16(A + (size_t)(m0 + ar0) * DMODEL + k0 + ao0 * 8, ldsA0);
    gload_lds16(A + (size_t)(m0 + 64 + ar0) * DMODEL + k0 + ao0 * 8, ldsA1);
    {
      short8 bs;
#pragma unroll
      for (int j = 0; j < 8; ++j)
        bs[j] = f2bs(Wb[(size_t)(k0 + bkg * 8 + j) * ldw + ncol + bn]);
      *(short8*)&Bsub[bn][bkg * 8] = bs;
    }
    __syncthreads();
    short8 af[4];
#pragma unroll
    for (int mi = 0; mi < 4; ++mi) {
      int r = wm + mi * 16 + mr;
      af[mi] = *(const short8*)&Asub[r][(quad ^ (r & 3)) * 8];
    }
    short8 bfr[2];
#pragma unroll
    for (int ni = 0; ni < 2; ++ni) {
      int r = wn + ni * 16 + mr;
      bfr[ni] = *(const short8*)&Bsub[r][quad * 8];
    }
#pragma unroll
    for (int mi = 0; mi < 4; ++mi)
#pragma unroll
      for (int ni = 0; ni < 2; ++ni)
        acc[mi][ni] = __builtin_amdgcn_mfma_f32_16x16x32_bf16(af[mi], bfr[ni], acc[mi][ni], 0, 0, 0);
    __syncthreads();
  }

#pragma unroll
  for (int mi = 0; mi < 4; ++mi) {
#pragma unroll
    for (int ni = 0; ni < 2; ++ni) {
#pragma unroll
      for (int r = 0; r < 4; ++r) {
        int gm = m0 + wm + mi * 16 + quad * 4 + r;
        int gnl = wn + ni * 16 + mr;
        float v = acc[mi][ni][r];
        if (bx < 128) {
          QKp[(size_t)gm * 8192 + bx * 64 + gnl] = f2b(v);
        } else {
          yqk[(size_t)gm * 256 + (bx - 128) * 64 + gnl] = v;
        }
      }
    }
  }
}

// ---------------------------------------------------------------------------
// K5b: table GEMM (bf16 B via global_load_lds):
//  z = side*32 + h (64 slabs). A = QKp + side*4096 + h*128 (lda 8192).
//  B = SWb[h] (128x128, K-contig). C = Tg + z*512*TCOLS (f32, ldc TCOLS),
//  store only gn<TCOLS with extra = RB[z][gn] added.
// ---------------------------------------------------------------------------
__global__ __launch_bounds__(256) void gemm_table(
    const bf16* __restrict__ QKp, const bf16* __restrict__ SWb,
    const float* __restrict__ RB, float* __restrict__ Tg) {
  __shared__ short Asub[128][32];
  __shared__ short Bsub[64][32];
  const int t = threadIdx.x;
  const int lane = t & 63;
  const int w = t >> 6;
  const int z = blockIdx.z;
  const int m0 = blockIdx.y * 128, n0 = blockIdx.x * 64;
  const int wm = (w >> 1) * 64, wn = (w & 1) * 32;
  const bf16* Ag = QKp + (size_t)(z >> 5) * 4096 + (size_t)(z & 31) * 128;
  const bf16* Bg = SWb + (size_t)(z & 31) * 128 * 128;

  const int ar0 = t >> 2;
  const int as0 = t & 3;
  const int ao0 = as0 ^ (ar0 & 3);
  char* AsubB = (char*)&Asub[0][0];
  char* BsubB = (char*)&Bsub[0][0];
  char* ldsA0 = AsubB + w * 1024;
  char* ldsA1 = AsubB + 4096 + w * 1024;
  char* ldsB0 = BsubB + w * 1024;

  const int quad = lane >> 4, mr = lane & 15;
  f32x4 acc[4][2];
#pragma unroll
  for (int mi = 0; mi < 4; ++mi)
#pragma unroll
    for (int ni = 0; ni < 2; ++ni) acc[mi][ni] = (f32x4){0.f, 0.f, 0.f, 0.f};

  for (int k0 = 0; k0 < 128; k0 += 32) {
    gload_lds16(Ag + (size_t)(m0 + ar0) * 8192 + k0 + ao0 * 8, ldsA0);
    gload_lds16(Ag + (size_t)(m0 + 64 + ar0) * 8192 + k0 + ao0 * 8, ldsA1);
    gload_lds16(Bg + (size_t)(n0 + ar0) * 128 + k0 + ao0 * 8, ldsB0);
    __syncthreads();
    short8 af[4];
#pragma unroll
    for (int mi = 0; mi < 4; ++mi) {
      int r = wm + mi * 16 + mr;
      af[mi] = *(const short8*)&Asub[r][(quad ^ (r & 3)) * 8];
    }
    short8 bfr[2];
#pragma unroll
    for (int ni = 0; ni < 2; ++ni) {
      int r = wn + ni * 16 + mr;
      bfr[ni] = *(const short8*)&Bsub[r][(quad ^ (r & 3)) * 8];
    }
#pragma unroll
    for (int mi = 0; mi < 4; ++mi)
#pragma unroll
      for (int ni = 0; ni < 2; ++ni)
        acc[mi][ni] = __builtin_amdgcn_mfma_f32_16x16x32_bf16(af[mi], bfr[ni], acc[mi][ni], 0, 0, 0);
    __syncthreads();
  }

  float* Cz = Tg + (size_t)z * 512 * TCOLS;
  const float* ex = RB + (size_t)z * 128;
#pragma unroll
  for (int mi = 0; mi < 4; ++mi) {
#pragma unroll
    for (int ni = 0; ni < 2; ++ni) {
#pragma unroll
      for (int r = 0; r < 4; ++r) {
        int gm = m0 + wm + mi * 16 + quad * 4 + r;
        int gn = n0 + wn + ni * 16 + mr;
        if (gn < TCOLS) Cz[(size_t)gm * TCOLS + gn] = acc[mi][ni][r] + ex[gn];
      }
    }
  }
}

// ---------------------------------------------------------------------------
// MEGA: per 32x32 (q,k) tile, loop h: S=Q_h.K_h^T (MFMA) + table-lookup rel
// terms -> P[m][h] in LDS; then pair projection + epilogue -> out.
// 512 threads. LDS (bytes):
//   Qs [4][32][32]s @0       Ks @8192
//   Tq dbuf @16384/+10240    Tk dbuf @36864/+10240   (each 32 rows x 80 f32)
//   Ssc [32][33]f @57344     fmL [1024]s @61568   Pl [1024][40]s @63616
// total 145536
// ---------------------------------------------------------------------------
#define MEGA_LDS 145536
__global__ __launch_bounds__(512) void mega_kernel(
    const bf16* __restrict__ QKp, const float* __restrict__ Tg,
    const short* __restrict__ fm_tab, const bf16* __restrict__ WpT,
    const float* __restrict__ b_pair, const float* __restrict__ yqk,
    float* __restrict__ out) {
  extern __shared__ char sm[];
  short* Qs = (short*)(sm);
  short* Ks = (short*)(sm + 8192);
  float* Ssc = (float*)(sm + 57344);
  short* fmL = (short*)(sm + 61568);
  short* Pl = (short*)(sm + 63616);

  const int t = threadIdx.x;
  const int lane = t & 63, w = t >> 6;
  const int quad = lane >> 4, mr = lane & 15;
  const int q0 = (blockIdx.x >> 4) * 32;
  const int k0 = (blockIdx.x & 15) * 32;

  // ---- staging helpers ----
  const int c_ks = t >> 7;
  const int c_cc = t & 127;
  const int c_r = c_cc >> 2;
  const int c_pc = c_cc & 3;
  const int qk_col = c_ks * 32 + ((c_pc ^ (c_r & 3)) * 8);
  const int t_r0 = t / 20, t_p0 = t - t_r0 * 20;
  const int c2 = 512 + t;
  const int t_r1 = c2 / 20, t_p1 = c2 - t_r1 * 20;

#define STAGE_QK(h)                                                                   \
  {                                                                                   \
    gload_lds16(QKp + (size_t)(q0 + c_r) * 8192 + (h)*128 + qk_col, (char*)Qs + t * 16); \
    gload_lds16(QKp + (size_t)(k0 + c_r) * 8192 + 4096 + (h)*128 + qk_col,            \
                (char*)Ks + t * 16);                                                  \
  }
#define STAGE_T(h)                                                                    \
  {                                                                                   \
    char* dq = sm + 16384 + ((h)&1) * 10240;                                          \
    char* dk = sm + 36864 + ((h)&1) * 10240;                                          \
    const float* sq_ = Tg + (size_t)(h)*512 * TCOLS;                                  \
    const float* sk_ = Tg + (size_t)(32 + (h)) * 512 * TCOLS;                         \
    gload_lds16(sq_ + (size_t)(q0 + t_r0) * TCOLS + t_p0 * 4, dq + t * 16);           \
    gload_lds16(sk_ + (size_t)(k0 + t_r0) * TCOLS + t_p0 * 4, dk + t * 16);           \
    if (t < 128) {                                                                    \
      gload_lds16(sq_ + (size_t)(q0 + t_r1) * TCOLS + t_p1 * 4, dq + c2 * 16);        \
      gload_lds16(sk_ + (size_t)(k0 + t_r1) * TCOLS + t_p1 * 4, dk + c2 * 16);        \
    }                                                                                 \
  }

  // prologue
  if (t < 128) gload_lds16(fm_tab + t * 8, (char*)fmL + t * 16);
  STAGE_QK(0);
  STAGE_T(0);
  __syncthreads();

  // ---- hoist h-invariant pack indices (needs fmL, available after sync) ----
  int tqa[2], tqb[2], tqc[2], tka[2], tkb[2], tkc[2], ssco[2], plo[2];
  float sgn[2];
#pragma unroll
  for (int j = 0; j < 2; ++j) {
    int m = j * 512 + t;
    int qL = m >> 5, kL = m & 31;
    int pq = 512 + (k0 + kL) - (q0 + qL);
    int gq = fmL[pq], gk = fmL[1024 - pq];
    sgn[j] = (pq > 512) ? 1.f : ((pq < 512) ? -1.f : 0.f);
    tqa[j] = qL * TCOLS + gq;
    tqb[j] = qL * TCOLS + 33 + gq;
    tqc[j] = qL * TCOLS + 66;
    tka[j] = kL * TCOLS + gk;
    tkb[j] = kL * TCOLS + 33 + gk;
    tkc[j] = kL * TCOLS + 66;
    ssco[j] = qL * 33 + kL;
    plo[j] = m * 40;
  }

  for (int h = 0; h < 32; ++h) {
    // ---- compute S (waves 0..3) ----
    if (w < 4) {
      const int smi = w >> 1, sni = w & 1;
      const int ra = smi * 16 + mr, rb = sni * 16 + mr;
      f32x4 accS = (f32x4){0.f, 0.f, 0.f, 0.f};
#pragma unroll
      for (int ks = 0; ks < 4; ++ks) {
        short8 af = *(const short8*)&Qs[ks * 1024 + ra * 32 + ((quad ^ (ra & 3)) * 8)];
        short8 bfv = *(const short8*)&Ks[ks * 1024 + rb * 32 + ((quad ^ (rb & 3)) * 8)];
        accS = __builtin_amdgcn_mfma_f32_16x16x32_bf16(af, bfv, accS, 0, 0, 0);
      }
#pragma unroll
      for (int r = 0; r < 4; ++r)
        Ssc[(smi * 16 + quad * 4 + r) * 33 + sni * 16 + mr] = accS[r];
    }
    __syncthreads();
    if (h < 31) {
      STAGE_QK(h + 1);
      STAGE_T(h + 1);
    }
    // ---- pack column h of P ----
    {
      const float* tq = (const float*)(sm + 16384 + (h & 1) * 10240);
      const float* tk = (const float*)(sm + 36864 + (h & 1) * 10240);
#pragma unroll
      for (int j = 0; j < 2; ++j) {
        float vq = tq[tqa[j]] + sgn[j] * tq[tqb[j]] + tq[tqc[j]];
        float vk = tk[tka[j]] - sgn[j] * tk[tkb[j]] + tk[tkc[j]];
        float val = Ssc[ssco[j]] + 0.5f * (vq + vk);
        Pl[plo[j] + h] = f2bs(val);
      }
    }
    __syncthreads();
  }

  // ---- pair projection + epilogue ----
  short8 bfr[8];
  float bp[8];
#pragma unroll
  for (int ni = 0; ni < 8; ++ni) {
    int c = ni * 16 + mr;
    bfr[ni] = *(const short8*)(WpT + (size_t)c * 32 + quad * 8);
    bp[ni] = b_pair[c];
  }
#pragma unroll
  for (int mi = 0; mi < 8; ++mi) {
    int mb = w * 128 + mi * 16;
    short8 af = *(const short8*)&Pl[(mb + mr) * 40 + quad * 8];
    f32x4 acc[8];
#pragma unroll
    for (int ni = 0; ni < 8; ++ni)
      acc[ni] = __builtin_amdgcn_mfma_f32_16x16x32_bf16(
          af, bfr[ni], (f32x4){0.f, 0.f, 0.f, 0.f}, 0, 0, 0);
#pragma unroll
    for (int r = 0; r < 4; ++r) {
      int m = mb + quad * 4 + r;
      int q = q0 + (m >> 5), k = k0 + (m & 31);
      const float* yq = yqk + (size_t)q * 256;
      const float* yk = yqk + (size_t)k * 256 + 128;
      float* orow = out + ((size_t)q * 512 + k) * 128;
#pragma unroll
      for (int ni = 0; ni < 8; ++ni) {
        int c = ni * 16 + mr;
        orow[c] = acc[ni][r] + bp[ni] + yq[c] + yk[c];
      }
    }
  }
}

// ===========================================================================
extern "C" void kernel_launch(void* const* d_in, const int* in_sizes, int n_in,
                              void* d_out, int out_size, void* d_ws, size_t ws_size,
                              hipStream_t stream) {
  const float* x      = (const float*)d_in[0];
  const float* w_rms  = (const float*)d_in[1];
  const float* W_q    = (const float*)d_in[2];
  const float* W_k    = (const float*)d_in[3];
  const float* W_pos  = (const float*)d_in[4];
  const float* b_pos  = (const float*)d_in[5];
  const float* qrb    = (const float*)d_in[6];
  const float* krb    = (const float*)d_in[7];
  const float* W_yq   = (const float*)d_in[8];
  const float* W_yk   = (const float*)d_in[9];
  const float* W_pair = (const float*)d_in[10];
  const float* b_pair = (const float*)d_in[11];
  float* out = (float*)d_out;

  static bool attr_set = false;
  if (!attr_set) {
    (void)hipFuncSetAttribute((const void*)mega_kernel,
                              hipFuncAttributeMaxDynamicSharedMemorySize, MEGA_LDS);
    attr_set = true;
  }

  // ---- workspace layout (~42 MB) ----
  char* w = (char*)d_ws;
  bf16* xn   = (bf16*)w; w += (size_t)SPOOL * DMODEL * 2;       // 1.5 MB
  bf16* xg   = (bf16*)w; w += (size_t)SPOOL * DMODEL * 2;       // 1.5 MB
  bf16* QKp  = (bf16*)w; w += (size_t)SPOOL * 8192 * 2;         // 8.4 MB (Q|K)
  float* yqk = (float*)w; w += (size_t)SPOOL * 256 * 4;         // 0.5 MB
  bf16* WpT  = (bf16*)w; w += (size_t)HDIM * NHEADS * 2;        // 8 KB
  float* SW0 = (float*)w; w += (size_t)33 * HDTOT * 4;          // 0.54 MB
  float* SW1 = (float*)w; w += (size_t)33 * HDTOT * 4;          // 0.54 MB
  bf16* SWb  = (bf16*)w; w += (size_t)NHEADS * 128 * 128 * 2;   // 1.05 MB
  float* RB  = (float*)w; w += (size_t)64 * 128 * 4;            // 32 KB
  short* fm_tab = (short*)w; w += 1024 * 2;                     // 2 KB
  w = (char*)(((uintptr_t)w + 255) & ~(uintptr_t)255);
  float* Tg = (float*)w; w += (size_t)2 * NHEADS * SPOOL * TCOLS * 4;  // 26.2 MB

  // 1. pool + rms + gelu
  pool_rms_gelu_bf<<<SPOOL, 256, 0, stream>>>(x, w_rms, xn, xg);
  // 2. suffix sums + prep tables (SWb, RB, fm, WpT)
  suffix_kernel<<<HDTOT / 256, 256, 0, stream>>>(W_pos, SW0, SW1);
  prep_kernel<<<98, 256, 0, stream>>>(SW0, SW1, b_pos, qrb, krb, W_pair,
                                      SWb, RB, fm_tab, WpT);
  // 3. merged projections: Q|K (bf16) + yq|yk (f32), W read directly (f32)
  gemm_proj<<<dim3(132, SPOOL / 128), 256, 0, stream>>>(
      xn, xg, W_q, W_k, W_yq, W_yk, QKp, yqk);
  // 4. rel tables (both sides in one dispatch, z = side*32+h)
  gemm_table<<<dim3(128 / 64, SPOOL / 128, 64), 256, 0, stream>>>(QKp, SWb, RB, Tg);
  // 5. fused S + rel-lookup + pack + pair projection + epilogue
  mega_kernel<<<256, 512, MEGA_LDS, stream>>>(QKp, Tg, fm_tab, WpT, b_pair, yqk, out);
}